// Round 3
// baseline (1509.061 us; speedup 1.0000x reference)
//
#include <hip/hip_runtime.h>
#include <hip/hip_bf16.h>

#define NW 256
#define NDEPTH 10

// ---------------- fused forward: first fc + 10 residual blocks + last fc ----------------
__global__ __launch_bounds__(256) void forward_kernel(
    const float* __restrict__ x, const float* __restrict__ W1, const float* __restrict__ b1,
    const float* __restrict__ Wb, const float* __restrict__ bb,
    const float* __restrict__ Wl, const float* __restrict__ bl,
    float* __restrict__ out) {
  const int b = blockIdx.x;
  const int o = threadIdx.x;
  __shared__ __align__(16) float xs[784];
  __shared__ __align__(16) float ybuf[2][NW];

  for (int k = o; k < 784; k += 256) xs[k] = x[(size_t)b * 784 + k];
  __syncthreads();

  {
    const float* w1r = W1 + (size_t)o * 784;
    float s = b1[o];
    for (int k = 0; k < 784; k += 4) {
      float4 w = *(const float4*)(w1r + k);
      float4 xv = *(const float4*)(&xs[k]);
      s += w.x * xv.x + w.y * xv.y + w.z * xv.z + w.w * xv.w;
    }
    ybuf[0][o] = fmaxf(s, 0.f);
  }
  __syncthreads();

  int cur = 0;
  for (int d = 0; d < NDEPTH; ++d) {
    const float* wr = Wb + (size_t)d * NW * NW + (size_t)o * NW;
    const float* yc = ybuf[cur];
    float acc = bb[d * NW + o];
#pragma unroll 8
    for (int k = 0; k < NW; k += 4) {
      float4 w = *(const float4*)(wr + k);
      float4 yv = *(const float4*)(&yc[k]);
      acc += w.x * yv.x + w.y * yv.y + w.z * yv.z + w.w * yv.w;
    }
    float ynew = fmaxf(acc, 0.f) + yc[o];
    ybuf[cur ^ 1][o] = ynew;
    __syncthreads();
    cur ^= 1;
  }

  if (o < 10) {
    const float* wr = Wl + o * NW;
    const float* yc = ybuf[cur];
    float acc = bl[o];
    for (int k = 0; k < NW; k += 4) {
      float4 w = *(const float4*)(wr + k);
      float4 yv = *(const float4*)(&yc[k]);
      acc += w.x * yv.x + w.y * yv.y + w.z * yv.z + w.w * yv.w;
    }
    out[b * 10 + o] = acc;
  }
}

// ---------------- B = (I+W)^T (I+W) for all 10 blocks ----------------
__global__ void bmat_kernel(const float* __restrict__ Wb, float* __restrict__ Ball) {
  const int blk = blockIdx.x;        // 10 * 32
  const int k   = blk >> 5;
  const int r0  = (blk & 31) << 3;   // 8 rows per block
  const int c   = threadIdx.x;       // 256
  const float* W = Wb + (size_t)k * NW * NW;
  float acc[8] = {0.f,0.f,0.f,0.f,0.f,0.f,0.f,0.f};
  for (int j = 0; j < NW; ++j) {
    const float wc = W[j * NW + c];
#pragma unroll
    for (int rr = 0; rr < 8; ++rr) acc[rr] += wc * W[j * NW + r0 + rr];
  }
#pragma unroll
  for (int rr = 0; rr < 8; ++rr) {
    const int r = r0 + rr;
    float s = acc[rr] + W[c * NW + r] + W[r * NW + c] + ((r == c) ? 1.f : 0.f);
    Ball[(size_t)k * NW * NW + r * NW + c] = s;
  }
}

// ---------------- eigen kernel: 512 threads, Bv[128]/thread, 4 barriers/iter ----------------
// Numerics identical to the round-1 (validated) version: direct masked sumsq for
// norm2 (no full-minus-below cancellation), rcp-guarded Sturm q-recurrence.
__global__ __launch_bounds__(512, 2) void eig_kernel(const float* __restrict__ Ball,
                                                     float* __restrict__ sig) {
  const int blk = blockIdx.x;      // 0..9
  const int t = threadIdx.x;       // 0..511
  const int r = t & 255;           // owned row
  const int q = t >> 8;            // column half 0..1
  const int c0 = q << 7;           // 0 or 128

  __shared__ __align__(16) float vcol[NW];
  __shared__ __align__(16) float vv[NW];
  __shared__ __align__(16) float pp[NW];
  __shared__ __align__(16) float w2[2][NW];
  __shared__ float dd[NW];
  __shared__ float ee2[NW];
  __shared__ float red[2];
  __shared__ float red2[4];
  __shared__ float sc_tau;

  float Bv[128];
  {
    const float* src = Ball + (size_t)blk * NW * NW + (size_t)r * NW + c0;
#pragma unroll
    for (int g = 0; g < 32; ++g) {
      const float4 f = *(const float4*)(src + 4 * g);
      Bv[4*g+0] = f.x; Bv[4*g+1] = f.y; Bv[4*g+2] = f.z; Bv[4*g+3] = f.w;
    }
  }

  // initial: dump row 0, red[q] = masked sumsq over c > 0
  if (r == 0) {
    float ss = 0.f;
#pragma unroll
    for (int g = 0; g < 32; ++g) {
      *(float4*)&vcol[c0 + 4*g] = make_float4(Bv[4*g], Bv[4*g+1], Bv[4*g+2], Bv[4*g+3]);
#pragma unroll
      for (int j = 0; j < 4; ++j)
        if (c0 + 4*g + j > 0) ss += Bv[4*g+j] * Bv[4*g+j];
    }
    red[q] = ss;
  }
  __syncthreads();

  for (int i = 0; i < NW - 2; ++i) {
    // ---- P1: scalars + clean v in LDS (threads < 256) ----
    if (t < NW) {
      const float norm2 = red[0] + red[1];           // direct masked sum (c > i)
      const float head  = vcol[i + 1];
      const float alpha = -copysignf(sqrtf(norm2), head);
      const float v1    = head - alpha;
      vv[t] = (t <= i) ? 0.f : ((t == i + 1) ? v1 : vcol[t]);
      if (t == 0) {
        const float vn2 = norm2 - head * head + v1 * v1;
        sc_tau = (vn2 > 1e-30f) ? 2.f / vn2 : 0.f;
        dd[i] = vcol[i];
        ee2[i] = norm2;
      }
    }
    __syncthreads();

    // ---- P2: matvec partial (all 512) ----
    {
      float s = 0.f;
      if (r > i && c0 + 127 > i) {
#pragma unroll
        for (int g = 0; g < 32; ++g) {
          const float4 v4 = *(const float4*)&vv[c0 + 4*g];
          s += Bv[4*g]*v4.x + Bv[4*g+1]*v4.y + Bv[4*g+2]*v4.z + Bv[4*g+3]*v4.w;
        }
      }
      w2[q][r] = s;
    }
    __syncthreads();

    // ---- P3: p = tau*Bv, vp reduce (threads < 256) ----
    if (t < NW) {
      const float p = sc_tau * (w2[0][t] + w2[1][t]);
      pp[t] = p;
      float part = vv[t] * p;
#pragma unroll
      for (int off = 32; off; off >>= 1) part += __shfl_down(part, off);
      if ((t & 63) == 0) red2[t >> 6] = part;
    }
    __syncthreads();

    // ---- P4: rank-2 update + dump row i+1 (direct masked sumsq over c > i+1) ----
    {
      const float vp = red2[0] + red2[1] + red2[2] + red2[3];
      const float K = 0.5f * sc_tau * vp;
      const float vr = vv[r];
      const float wr_ = pp[r] - K * vr;
      if (r > i && c0 + 127 > i) {
#pragma unroll
        for (int g = 0; g < 32; ++g) {
          const float4 v4 = *(const float4*)&vv[c0 + 4*g];
          const float4 p4 = *(const float4*)&pp[c0 + 4*g];
          Bv[4*g+0] -= vr * (p4.x - K * v4.x) + wr_ * v4.x;
          Bv[4*g+1] -= vr * (p4.y - K * v4.y) + wr_ * v4.y;
          Bv[4*g+2] -= vr * (p4.z - K * v4.z) + wr_ * v4.z;
          Bv[4*g+3] -= vr * (p4.w - K * v4.w) + wr_ * v4.w;
        }
      }
      if (r == i + 1) {
        float ss = 0.f;
#pragma unroll
        for (int g = 0; g < 32; ++g) {
          *(float4*)&vcol[c0 + 4*g] = make_float4(Bv[4*g], Bv[4*g+1], Bv[4*g+2], Bv[4*g+3]);
          const float s4 = Bv[4*g]*Bv[4*g] + Bv[4*g+1]*Bv[4*g+1]
                         + Bv[4*g+2]*Bv[4*g+2] + Bv[4*g+3]*Bv[4*g+3];
          const int cbase = c0 + 4*g;
          if (cbase > i + 1) {
            ss += s4;                       // whole group above boundary (uniform cond)
          } else if (cbase + 3 > i + 1) {   // straddling group: scalar masked
#pragma unroll
            for (int j = 0; j < 4; ++j)
              if (cbase + j > i + 1) ss += Bv[4*g+j] * Bv[4*g+j];
          }
        }
        red[q] = ss;
      }
    }
    __syncthreads();
  }

  // epilogue: vcol = row 254; red = masked sumsq over c > 254 (= B[254][255]^2)
  if (t == 0) {
    dd[254] = vcol[254];
    ee2[254] = red[0] + red[1];
    ee2[255] = 0.f;
  }
  if (r == 255 && q == 1) dd[255] = Bv[127];
  __syncthreads();

  // Gershgorin bounds (all 512 threads)
  {
    const float ej  = (r < 255) ? sqrtf(ee2[r]) : 0.f;
    const float ejm = (r > 0) ? sqrtf(ee2[r - 1]) : 0.f;
    float lo_ = dd[r] - ej - ejm;
    float hi_ = dd[r] + ej + ejm;
#pragma unroll
    for (int off = 32; off; off >>= 1) {
      lo_ = fminf(lo_, __shfl_down(lo_, off));
      hi_ = fmaxf(hi_, __shfl_down(hi_, off));
    }
    float* gb = &w2[0][0];
    if ((t & 63) == 0) { gb[t >> 6] = lo_; gb[8 + (t >> 6)] = hi_; }
  }
  __syncthreads();

  // bisection: round-1 validated rcp-guarded q-recurrence, 30 iters
  if (t < NW) {
    const float* gb = &w2[0][0];
    float lo = gb[0], hi = gb[8];
#pragma unroll
    for (int u = 1; u < 8; ++u) { lo = fminf(lo, gb[u]); hi = fmaxf(hi, gb[8 + u]); }
    lo = fminf(lo, 0.f);   // B is PSD
    const int target = t;
    for (int it = 0; it < 30; ++it) {
      const float mid = 0.5f * (lo + hi);
      int cnt = 0;
      float qv = dd[0] - mid;
      cnt += (qv < 0.f);
      for (int j = 1; j < NW; ++j) {
        float denom = (fabsf(qv) < 1e-20f) ? -1e-20f : qv;
        qv = dd[j] - mid - ee2[j - 1] * __builtin_amdgcn_rcpf(denom);
        cnt += (qv < 0.f);
      }
      if (cnt > target) hi = mid; else lo = mid;
    }
    const float lam = 0.5f * (lo + hi);
    sig[blk * NW + (255 - t)] = sqrtf(fmaxf(lam, 0.f));  // descending
  }
}

// ---------------- mean over blocks, broadcast over batch ----------------
__global__ void sig_avg_kernel(const float* __restrict__ sig, float* __restrict__ out_all) {
  const int b = blockIdx.x;   // 256
  const int j = threadIdx.x;  // 256
  float s = 0.f;
#pragma unroll
  for (int k = 0; k < NDEPTH; ++k) s += sig[k * NW + j];
  out_all[b * NW + j] = s * 0.1f;
}

extern "C" void kernel_launch(void* const* d_in, const int* in_sizes, int n_in,
                              void* d_out, int out_size, void* d_ws, size_t ws_size,
                              hipStream_t stream) {
  const float* x  = (const float*)d_in[0];
  const float* W1 = (const float*)d_in[1];
  const float* b1 = (const float*)d_in[2];
  const float* Wb = (const float*)d_in[3];
  const float* bb = (const float*)d_in[4];
  const float* Wl = (const float*)d_in[5];
  const float* bl = (const float*)d_in[6];
  float* out = (float*)d_out;               // 2560 + 65536

  float* ws = (float*)d_ws;
  float* Ball = ws;                 // 10*65536
  float* sigw = ws + 655360;        // 10*256

  bmat_kernel<<<dim3(NDEPTH * 32), dim3(256), 0, stream>>>(Wb, Ball);
  forward_kernel<<<dim3(256), dim3(256), 0, stream>>>(x, W1, b1, Wb, bb, Wl, bl, out);
  eig_kernel<<<dim3(NDEPTH), dim3(512), 0, stream>>>(Ball, sigw);
  sig_avg_kernel<<<dim3(256), dim3(256), 0, stream>>>(sigw, out + 2560);
}

// Round 4
// 1147.091 us; speedup vs baseline: 1.3156x; 1.3156x over previous
//
#include <hip/hip_runtime.h>
#include <hip/hip_bf16.h>

#define NW 256
#define NDEPTH 10

// float readlane helper (broadcast lane -> SGPR, used as the scalar operand of v_fmac)
__device__ __forceinline__ float rlf(float x, int lane) {
  return __int_as_float(__builtin_amdgcn_readlane(__float_as_int(x), lane));
}

// ---------------- fused forward: first fc + 10 residual blocks + last fc ----------------
__global__ __launch_bounds__(256) void forward_kernel(
    const float* __restrict__ x, const float* __restrict__ W1, const float* __restrict__ b1,
    const float* __restrict__ Wb, const float* __restrict__ bb,
    const float* __restrict__ Wl, const float* __restrict__ bl,
    float* __restrict__ out) {
  const int b = blockIdx.x;
  const int o = threadIdx.x;
  __shared__ __align__(16) float xs[784];
  __shared__ __align__(16) float ybuf[2][NW];

  for (int k = o; k < 784; k += 256) xs[k] = x[(size_t)b * 784 + k];
  __syncthreads();

  {
    const float* w1r = W1 + (size_t)o * 784;
    float s = b1[o];
    for (int k = 0; k < 784; k += 4) {
      float4 w = *(const float4*)(w1r + k);
      float4 xv = *(const float4*)(&xs[k]);
      s += w.x * xv.x + w.y * xv.y + w.z * xv.z + w.w * xv.w;
    }
    ybuf[0][o] = fmaxf(s, 0.f);
  }
  __syncthreads();

  int cur = 0;
  for (int d = 0; d < NDEPTH; ++d) {
    const float* wr = Wb + (size_t)d * NW * NW + (size_t)o * NW;
    const float* yc = ybuf[cur];
    float acc = bb[d * NW + o];
#pragma unroll 8
    for (int k = 0; k < NW; k += 4) {
      float4 w = *(const float4*)(wr + k);
      float4 yv = *(const float4*)(&yc[k]);
      acc += w.x * yv.x + w.y * yv.y + w.z * yv.z + w.w * yv.w;
    }
    float ynew = fmaxf(acc, 0.f) + yc[o];
    ybuf[cur ^ 1][o] = ynew;
    __syncthreads();
    cur ^= 1;
  }

  if (o < 10) {
    const float* wr = Wl + o * NW;
    const float* yc = ybuf[cur];
    float acc = bl[o];
    for (int k = 0; k < NW; k += 4) {
      float4 w = *(const float4*)(wr + k);
      float4 yv = *(const float4*)(&yc[k]);
      acc += w.x * yv.x + w.y * yv.y + w.z * yv.z + w.w * yv.w;
    }
    out[b * 10 + o] = acc;
  }
}

// ---------------- B = (I+W)^T (I+W) for all 10 blocks ----------------
__global__ void bmat_kernel(const float* __restrict__ Wb, float* __restrict__ Ball) {
  const int blk = blockIdx.x;        // 10 * 32
  const int k   = blk >> 5;
  const int r0  = (blk & 31) << 3;   // 8 rows per block
  const int c   = threadIdx.x;       // 256
  const float* W = Wb + (size_t)k * NW * NW;
  float acc[8] = {0.f,0.f,0.f,0.f,0.f,0.f,0.f,0.f};
  for (int j = 0; j < NW; ++j) {
    const float wc = W[j * NW + c];
#pragma unroll
    for (int rr = 0; rr < 8; ++rr) acc[rr] += wc * W[j * NW + r0 + rr];
  }
#pragma unroll
  for (int rr = 0; rr < 8; ++rr) {
    const int r = r0 + rr;
    float s = acc[rr] + W[c * NW + r] + W[r * NW + c] + ((r == c) ? 1.f : 0.f);
    Ball[(size_t)k * NW * NW + r * NW + c] = s;
  }
}

// ---------------- eigen kernel v3: readlane broadcast, 2 barriers/iter ----------------
// Numerics = R3's validated f32 path (direct masked norm2, K = 0.5*tau*(v^T p),
// rcp-guarded Sturm bisection). Broadcast of v/p via per-lane ds_read_b64 +
// v_readlane (VALU pipe) instead of uniform-address ds_read_b128 (LDS pipe).
__global__ __launch_bounds__(512, 2) void eig_kernel(const float* __restrict__ Ball,
                                                     float* __restrict__ sig) {
  const int blk = blockIdx.x;      // 0..9
  const int t = threadIdx.x;       // 0..511
  const int r = t & 255;           // owned row
  const int q = t >> 8;            // column half 0/1
  const int c0 = q << 7;           // 0 or 128
  const int l = t & 63;            // lane in wave
  const int g = (t >> 6) & 3;      // row group (rows 64g..64g+63)

  __shared__ __align__(16) float vcol[NW];      // current pivot row of B
  __shared__ __align__(16) float w2[2][NW];     // matvec partials per half
  __shared__ float dd[NW];
  __shared__ float ee2[NW];

  float Bv[128];
  {
    const float* src = Ball + (size_t)blk * NW * NW + (size_t)r * NW + c0;
#pragma unroll
    for (int gg = 0; gg < 32; ++gg) {
      const float4 f = *(const float4*)(src + 4 * gg);
      Bv[4*gg+0] = f.x; Bv[4*gg+1] = f.y; Bv[4*gg+2] = f.z; Bv[4*gg+3] = f.w;
    }
  }

  // initial dump of row 0 (both chunks)
  if (r == 0) {
#pragma unroll
    for (int gg = 0; gg < 32; ++gg)
      *(float4*)&vcol[c0 + 4*gg] = make_float4(Bv[4*gg], Bv[4*gg+1], Bv[4*gg+2], Bv[4*gg+3]);
  }
  __syncthreads();

  for (int i = 0; i < NW - 2; ++i) {
    const bool wave_dead = (64 * g + 63 <= i);
    float vA = 0.f, vB = 0.f, vhr = 0.f, tau = 0.f;
    float v00 = 0.f, v01 = 0.f, v10 = 0.f, v11 = 0.f;

    // ===== Phase A: per-wave norm2/tau, masked v-hat, matvec via readlane =====
    if (!wave_dead) {
      const float2 cp0 = *(const float2*)&vcol[2 * l];        // cols 2l, 2l+1
      const float2 cp1 = *(const float2*)&vcol[128 + 2 * l];  // cols 128+2l, 128+2l+1
      const float vcr = vcol[r];
      const float head = vcol[i + 1];
      const int ca = 2 * l, cb = 128 + 2 * l;

      // norm2 = sum_{c>i} vcol[c]^2, reduced within the wave (identical in all waves)
      float nsq = 0.f;
      if (ca     > i) nsq += cp0.x * cp0.x;
      if (ca + 1 > i) nsq += cp0.y * cp0.y;
      if (cb     > i) nsq += cp1.x * cp1.x;
      if (cb + 1 > i) nsq += cp1.y * cp1.y;
#pragma unroll
      for (int off = 1; off < 64; off <<= 1) nsq += __shfl_xor(nsq, off);
      const float norm2 = nsq;
      const float alpha = -copysignf(sqrtf(norm2), head);
      const float v1 = head - alpha;
      const float vn2 = norm2 - head * head + v1 * v1;
      tau = (vn2 > 1e-30f) ? 2.f / vn2 : 0.f;
      if (t == 192) { dd[i] = vcol[i]; ee2[i] = norm2; }   // t=192: never-dead wave

      // masked v-hat values
      v00 = (ca     <= i) ? 0.f : ((ca     == i + 1) ? v1 : cp0.x);
      v01 = (ca + 1 <= i) ? 0.f : ((ca + 1 == i + 1) ? v1 : cp0.y);
      v10 = (cb     <= i) ? 0.f : ((cb     == i + 1) ? v1 : cp1.x);
      v11 = (cb + 1 <= i) ? 0.f : ((cb + 1 == i + 1) ? v1 : cp1.y);
      vhr = (r <= i) ? 0.f : ((r == i + 1) ? v1 : vcr);
      vA = q ? v10 : v00;
      vB = q ? v11 : v01;

      float accT = 0.f;
      if (c0 + 127 > i) {     // chunk live
        float a0 = 0.f, a1 = 0.f, a2 = 0.f, a3 = 0.f;
#pragma unroll
        for (int j = 0; j < 128; j += 4) {
          const int ln = j >> 1;
          a0 = fmaf(Bv[j],     rlf(vA, ln),     a0);
          a1 = fmaf(Bv[j + 1], rlf(vB, ln),     a1);
          a2 = fmaf(Bv[j + 2], rlf(vA, ln + 1), a2);
          a3 = fmaf(Bv[j + 3], rlf(vB, ln + 1), a3);
        }
        accT = (a0 + a1) + (a2 + a3);
      }
      w2[q][r] = accT;
    }
    __syncthreads();

    // ===== Phase B: p = tau*B*v, K, rank-2 update via readlane, dump row i+1 =====
    if (!wave_dead) {
      const float2 u0a = *(const float2*)&w2[0][2 * l];
      const float2 u1a = *(const float2*)&w2[1][2 * l];
      const float2 u0b = *(const float2*)&w2[0][128 + 2 * l];
      const float2 u1b = *(const float2*)&w2[1][128 + 2 * l];
      const float p00 = tau * (u0a.x + u1a.x);
      const float p01 = tau * (u0a.y + u1a.y);
      const float p10 = tau * (u0b.x + u1b.x);
      const float p11 = tau * (u0b.y + u1b.y);
      const float pr = tau * (w2[0][r] + w2[1][r]);

      float kp = v00 * p00 + v01 * p01 + v10 * p10 + v11 * p11;
#pragma unroll
      for (int off = 1; off < 64; off <<= 1) kp += __shfl_xor(kp, off);
      const float K = 0.5f * tau * kp;

      const float pA = q ? p10 : p00;
      const float pB = q ? p11 : p01;
      const float s1n = -vhr;
      const float s2n = -(pr - 2.f * K * vhr);

      if (c0 + 127 > i) {
#pragma unroll
        for (int j = 0; j < 128; j += 2) {
          const int ln = j >> 1;
          const float pce = rlf(pA, ln), pco = rlf(pB, ln);
          const float vce = rlf(vA, ln), vco = rlf(vB, ln);
          Bv[j]     = fmaf(s1n, pce, Bv[j]);
          Bv[j]     = fmaf(s2n, vce, Bv[j]);
          Bv[j + 1] = fmaf(s1n, pco, Bv[j + 1]);
          Bv[j + 1] = fmaf(s2n, vco, Bv[j + 1]);
        }
      }
      // dump row i+1 (only chunks containing cols >= i+1)
      if (r == i + 1 && c0 + 127 >= i + 1) {
#pragma unroll
        for (int gg = 0; gg < 32; ++gg)
          *(float4*)&vcol[c0 + 4*gg] = make_float4(Bv[4*gg], Bv[4*gg+1], Bv[4*gg+2], Bv[4*gg+3]);
      }
    }
    __syncthreads();
  }

  // epilogue: trailing 2x2 block
  if (t == 0) {
    dd[254] = vcol[254];
    ee2[254] = vcol[255] * vcol[255];
    ee2[255] = 0.f;
  }
  if (r == 255 && q == 1) dd[255] = Bv[127];
  __syncthreads();

  // Gershgorin bounds (all 512 threads)
  {
    const float ej  = (r < 255) ? sqrtf(ee2[r]) : 0.f;
    const float ejm = (r > 0) ? sqrtf(ee2[r - 1]) : 0.f;
    float lo_ = dd[r] - ej - ejm;
    float hi_ = dd[r] + ej + ejm;
#pragma unroll
    for (int off = 32; off; off >>= 1) {
      lo_ = fminf(lo_, __shfl_down(lo_, off));
      hi_ = fmaxf(hi_, __shfl_down(hi_, off));
    }
    float* gb = &w2[0][0];
    if ((t & 63) == 0) { gb[t >> 6] = lo_; gb[8 + (t >> 6)] = hi_; }
  }
  __syncthreads();

  // bisection: rcp-guarded Sturm q-recurrence (validated), 24 iters
  if (t < NW) {
    const float* gb = &w2[0][0];
    float lo = gb[0], hi = gb[8];
#pragma unroll
    for (int u = 1; u < 8; ++u) { lo = fminf(lo, gb[u]); hi = fmaxf(hi, gb[8 + u]); }
    lo = fminf(lo, 0.f);   // B is PSD
    const int target = t;
    for (int it = 0; it < 24; ++it) {
      const float mid = 0.5f * (lo + hi);
      int cnt = 0;
      float qv = dd[0] - mid;
      cnt += (qv < 0.f);
      for (int j = 1; j < NW; ++j) {
        float denom = (fabsf(qv) < 1e-20f) ? -1e-20f : qv;
        qv = dd[j] - mid - ee2[j - 1] * __builtin_amdgcn_rcpf(denom);
        cnt += (qv < 0.f);
      }
      if (cnt > target) hi = mid; else lo = mid;
    }
    const float lam = 0.5f * (lo + hi);
    sig[blk * NW + (255 - t)] = sqrtf(fmaxf(lam, 0.f));  // descending
  }
}

// ---------------- mean over blocks, broadcast over batch ----------------
__global__ void sig_avg_kernel(const float* __restrict__ sig, float* __restrict__ out_all) {
  const int b = blockIdx.x;   // 256
  const int j = threadIdx.x;  // 256
  float s = 0.f;
#pragma unroll
  for (int k = 0; k < NDEPTH; ++k) s += sig[k * NW + j];
  out_all[b * NW + j] = s * 0.1f;
}

extern "C" void kernel_launch(void* const* d_in, const int* in_sizes, int n_in,
                              void* d_out, int out_size, void* d_ws, size_t ws_size,
                              hipStream_t stream) {
  const float* x  = (const float*)d_in[0];
  const float* W1 = (const float*)d_in[1];
  const float* b1 = (const float*)d_in[2];
  const float* Wb = (const float*)d_in[3];
  const float* bb = (const float*)d_in[4];
  const float* Wl = (const float*)d_in[5];
  const float* bl = (const float*)d_in[6];
  float* out = (float*)d_out;               // 2560 + 65536

  float* ws = (float*)d_ws;
  float* Ball = ws;                 // 10*65536
  float* sigw = ws + 655360;        // 10*256

  bmat_kernel<<<dim3(NDEPTH * 32), dim3(256), 0, stream>>>(Wb, Ball);
  forward_kernel<<<dim3(256), dim3(256), 0, stream>>>(x, W1, b1, Wb, bb, Wl, bl, out);
  eig_kernel<<<dim3(NDEPTH), dim3(512), 0, stream>>>(Ball, sigw);
  sig_avg_kernel<<<dim3(256), dim3(256), 0, stream>>>(sigw, out + 2560);
}

// Round 5
// 996.851 us; speedup vs baseline: 1.5138x; 1.1507x over previous
//
#include <hip/hip_runtime.h>
#include <hip/hip_bf16.h>

#define NW 256
#define NDEPTH 10

// float readlane broadcast (lane index is a compile-time constant in all uses)
__device__ __forceinline__ float rlf(float x, int lane) {
  return __int_as_float(__builtin_amdgcn_readlane(__float_as_int(x), lane));
}

// ---------------- fused forward: first fc + 10 residual blocks + last fc ----------------
__global__ __launch_bounds__(256) void forward_kernel(
    const float* __restrict__ x, const float* __restrict__ W1, const float* __restrict__ b1,
    const float* __restrict__ Wb, const float* __restrict__ bb,
    const float* __restrict__ Wl, const float* __restrict__ bl,
    float* __restrict__ out) {
  const int b = blockIdx.x;
  const int o = threadIdx.x;
  __shared__ __align__(16) float xs[784];
  __shared__ __align__(16) float ybuf[2][NW];

  for (int k = o; k < 784; k += 256) xs[k] = x[(size_t)b * 784 + k];
  __syncthreads();

  {
    const float* w1r = W1 + (size_t)o * 784;
    float s = b1[o];
    for (int k = 0; k < 784; k += 4) {
      float4 w = *(const float4*)(w1r + k);
      float4 xv = *(const float4*)(&xs[k]);
      s += w.x * xv.x + w.y * xv.y + w.z * xv.z + w.w * xv.w;
    }
    ybuf[0][o] = fmaxf(s, 0.f);
  }
  __syncthreads();

  int cur = 0;
  for (int d = 0; d < NDEPTH; ++d) {
    const float* wr = Wb + (size_t)d * NW * NW + (size_t)o * NW;
    const float* yc = ybuf[cur];
    float acc = bb[d * NW + o];
#pragma unroll 8
    for (int k = 0; k < NW; k += 4) {
      float4 w = *(const float4*)(wr + k);
      float4 yv = *(const float4*)(&yc[k]);
      acc += w.x * yv.x + w.y * yv.y + w.z * yv.z + w.w * yv.w;
    }
    float ynew = fmaxf(acc, 0.f) + yc[o];
    ybuf[cur ^ 1][o] = ynew;
    __syncthreads();
    cur ^= 1;
  }

  if (o < 10) {
    const float* wr = Wl + o * NW;
    const float* yc = ybuf[cur];
    float acc = bl[o];
    for (int k = 0; k < NW; k += 4) {
      float4 w = *(const float4*)(wr + k);
      float4 yv = *(const float4*)(&yc[k]);
      acc += w.x * yv.x + w.y * yv.y + w.z * yv.z + w.w * yv.w;
    }
    out[b * 10 + o] = acc;
  }
}

// ---------------- B = (I+W)^T (I+W) for all 10 blocks ----------------
__global__ void bmat_kernel(const float* __restrict__ Wb, float* __restrict__ Ball) {
  const int blk = blockIdx.x;        // 10 * 32
  const int k   = blk >> 5;
  const int r0  = (blk & 31) << 3;   // 8 rows per block
  const int c   = threadIdx.x;       // 256
  const float* W = Wb + (size_t)k * NW * NW;
  float acc[8] = {0.f,0.f,0.f,0.f,0.f,0.f,0.f,0.f};
  for (int j = 0; j < NW; ++j) {
    const float wc = W[j * NW + c];
#pragma unroll
    for (int rr = 0; rr < 8; ++rr) acc[rr] += wc * W[j * NW + r0 + rr];
  }
#pragma unroll
  for (int rr = 0; rr < 8; ++rr) {
    const int r = r0 + rr;
    float s = acc[rr] + W[c * NW + r] + W[r * NW + c] + ((r == c) ? 1.f : 0.f);
    Ball[(size_t)k * NW * NW + r * NW + c] = s;
  }
}

// ---------------- eigen kernel v4: 1024 threads, Bv[64]/thread, trimmed, readlane ----------------
// Numerics = validated R4 path (direct masked norm2, K = 0.5*tau*(v^T p) with
// v^T p = tau * v^T B v, rcp-guarded Sturm bisection).
__global__ __launch_bounds__(1024, 4) void eig_kernel(const float* __restrict__ Ball,
                                                      float* __restrict__ sig) {
  const int blk = blockIdx.x;     // 0..9
  const int t = threadIdx.x;      // 0..1023
  const int l = t & 63;           // lane
  const int wid = t >> 6;         // wave 0..15
  const int q = t >> 8;           // column chunk 0..3
  const int g = wid & 3;          // row group 0..3
  const int r = (g << 6) + l;     // owned row
  const int c0 = q << 6;          // chunk base column

  __shared__ __align__(16) float vcol[NW];
  __shared__ __align__(16) float w4[4][NW];
  __shared__ __align__(16) float kpart[16];
  __shared__ __align__(16) float dd[NW];
  __shared__ __align__(16) float ee2[NW];

  float Bv[64];
  {
    const float* src = Ball + (size_t)blk * NW * NW + (size_t)r * NW + c0;
#pragma unroll
    for (int gg = 0; gg < 16; ++gg) {
      const float4 f = *(const float4*)(src + 4 * gg);
      Bv[4*gg+0] = f.x; Bv[4*gg+1] = f.y; Bv[4*gg+2] = f.z; Bv[4*gg+3] = f.w;
    }
  }

  // initial dump of row 0 (4 threads, one per chunk)
  if (r == 0) {
#pragma unroll
    for (int gg = 0; gg < 16; ++gg)
      *(float4*)&vcol[c0 + 4*gg] = make_float4(Bv[4*gg], Bv[4*gg+1], Bv[4*gg+2], Bv[4*gg+3]);
  }
  __syncthreads();

  for (int i = 0; i < NW - 2; ++i) {
    const bool alive = ((g << 6) + 63 > i);
    float tau = 0.f, vmk = 0.f, vhr = 0.f;

    // ===== Phase A: norm2/tau per wave, masked v-hat, matvec partial =====
    if (alive) {
      const float a0 = vcol[l];
      const float a1 = vcol[64 + l];
      const float a2 = vcol[128 + l];
      const float a3 = vcol[192 + l];
      const float head = vcol[i + 1];

      float nsq = 0.f;
      nsq += (l       > i) ? a0 * a0 : 0.f;
      nsq += (64 + l  > i) ? a1 * a1 : 0.f;
      nsq += (128 + l > i) ? a2 * a2 : 0.f;
      nsq += (192 + l > i) ? a3 * a3 : 0.f;
#pragma unroll
      for (int off = 1; off < 64; off <<= 1) nsq += __shfl_xor(nsq, off);
      const float norm2 = nsq;
      const float alpha = -copysignf(sqrtf(norm2), head);
      const float v1 = head - alpha;
      const float vn2 = norm2 - head * head + v1 * v1;
      tau = (vn2 > 1e-30f) ? 2.f / vn2 : 0.f;
      if (t == 960) { dd[i] = vcol[i]; ee2[i] = norm2; }  // wave 15: alive for all i

      // own-column and own-row vcol values via uniform selects (no extra LDS reads)
      const float aq  = (q == 0) ? a0 : (q == 1) ? a1 : (q == 2) ? a2 : a3;
      const float vcr = (g == 0) ? a0 : (g == 1) ? a1 : (g == 2) ? a2 : a3;
      const int c = c0 + l;
      vmk = (c <= i) ? 0.f : ((c == i + 1) ? v1 : aq);
      vhr = (r <= i) ? 0.f : ((r == i + 1) ? v1 : vcr);

      // matvec partial over live 16-col sub-blocks
      float acc = 0.f;
#pragma unroll
      for (int sb = 0; sb < 4; ++sb) {
        if (c0 + 16 * sb + 15 > i) {        // wave-uniform
          float a = 0.f;
#pragma unroll
          for (int jj = 0; jj < 16; ++jj) {
            const int j = 16 * sb + jj;
            a = fmaf(Bv[j], rlf(vmk, j), a);
          }
          acc += a;
        }
      }
      w4[q][r] = acc;

      // v^T B v partial: sum over this wave's (row, chunk) pairs
      float kv = vhr * acc;
#pragma unroll
      for (int off = 1; off < 64; off <<= 1) kv += __shfl_xor(kv, off);
      if (l == 0) kpart[wid] = kv;
    } else if (l == 0) {
      kpart[wid] = 0.f;
    }
    __syncthreads();

    // ===== Phase B: p assembly, K, rank-2 update, dump row i+1 =====
    if (alive) {
      const int c = c0 + l;
      const float pc  = tau * (w4[0][c] + w4[1][c] + w4[2][c] + w4[3][c]);  // p at own column
      const float pr_ = tau * (w4[0][r] + w4[1][r] + w4[2][r] + w4[3][r]);  // p at own row
      const float4 k0 = *(const float4*)&kpart[0];
      const float4 k1 = *(const float4*)&kpart[4];
      const float4 k2 = *(const float4*)&kpart[8];
      const float4 k3 = *(const float4*)&kpart[12];
      const float vBv = ((k0.x + k0.y) + (k0.z + k0.w)) + ((k1.x + k1.y) + (k1.z + k1.w))
                      + ((k2.x + k2.y) + (k2.z + k2.w)) + ((k3.x + k3.y) + (k3.z + k3.w));
      const float K = 0.5f * tau * tau * vBv;   // = 0.5*tau*(v^T p)
      const float s1n = -vhr;
      const float s2n = -(pr_ - 2.f * K * vhr);

#pragma unroll
      for (int sb = 0; sb < 4; ++sb) {
        if (c0 + 16 * sb + 15 > i) {        // wave-uniform
#pragma unroll
          for (int jj = 0; jj < 16; ++jj) {
            const int j = 16 * sb + jj;
            Bv[j] = fmaf(s1n, rlf(pc, j), Bv[j]);
            Bv[j] = fmaf(s2n, rlf(vmk, j), Bv[j]);
          }
        }
      }
      // dump row i+1 chunks that contain any column >= i+1  (>= is essential)
      if (r == i + 1 && c0 + 63 >= i + 1) {
#pragma unroll
        for (int gg = 0; gg < 16; ++gg)
          *(float4*)&vcol[c0 + 4*gg] = make_float4(Bv[4*gg], Bv[4*gg+1], Bv[4*gg+2], Bv[4*gg+3]);
      }
    }
    __syncthreads();
  }

  // epilogue: trailing 2x2 block
  if (t == 0) {
    dd[254] = vcol[254];
    ee2[254] = vcol[255] * vcol[255];
    ee2[255] = 0.f;
  }
  if (t == 1023) dd[255] = Bv[63];   // r=255, q=3 -> column 255
  __syncthreads();

  // Gershgorin bounds (threads < 256; waves 0..3)
  if (t < NW) {
    const float ej  = (t < 255) ? sqrtf(ee2[t]) : 0.f;
    const float ejm = (t > 0) ? sqrtf(ee2[t - 1]) : 0.f;
    float lo_ = dd[t] - ej - ejm;
    float hi_ = dd[t] + ej + ejm;
#pragma unroll
    for (int off = 32; off; off >>= 1) {
      lo_ = fminf(lo_, __shfl_down(lo_, off));
      hi_ = fmaxf(hi_, __shfl_down(hi_, off));
    }
    if (l == 0) { kpart[wid] = lo_; kpart[8 + wid] = hi_; }
  }
  __syncthreads();

  // bisection: validated rcp-guarded Sturm q-recurrence, 18 iters (waves 0..3, one per SIMD)
  if (t < NW) {
    float lo = fminf(fminf(kpart[0], kpart[1]), fminf(kpart[2], kpart[3]));
    float hi = fmaxf(fmaxf(kpart[8], kpart[9]), fmaxf(kpart[10], kpart[11]));
    lo = fminf(lo, 0.f);   // B is PSD
    const int target = t;
    for (int it = 0; it < 18; ++it) {
      const float mid = 0.5f * (lo + hi);
      int cnt = 0;
      float qv = dd[0] - mid;
      cnt += (qv < 0.f);
      for (int j = 1; j < NW; ++j) {
        const float denom = (fabsf(qv) < 1e-20f) ? -1e-20f : qv;
        qv = dd[j] - mid - ee2[j - 1] * __builtin_amdgcn_rcpf(denom);
        cnt += (qv < 0.f);
      }
      if (cnt > target) hi = mid; else lo = mid;
    }
    const float lam = 0.5f * (lo + hi);
    sig[blk * NW + (255 - target)] = sqrtf(fmaxf(lam, 0.f));  // descending
  }
}

// ---------------- mean over blocks, broadcast over batch ----------------
__global__ void sig_avg_kernel(const float* __restrict__ sig, float* __restrict__ out_all) {
  const int b = blockIdx.x;   // 256
  const int j = threadIdx.x;  // 256
  float s = 0.f;
#pragma unroll
  for (int k = 0; k < NDEPTH; ++k) s += sig[k * NW + j];
  out_all[b * NW + j] = s * 0.1f;
}

extern "C" void kernel_launch(void* const* d_in, const int* in_sizes, int n_in,
                              void* d_out, int out_size, void* d_ws, size_t ws_size,
                              hipStream_t stream) {
  const float* x  = (const float*)d_in[0];
  const float* W1 = (const float*)d_in[1];
  const float* b1 = (const float*)d_in[2];
  const float* Wb = (const float*)d_in[3];
  const float* bb = (const float*)d_in[4];
  const float* Wl = (const float*)d_in[5];
  const float* bl = (const float*)d_in[6];
  float* out = (float*)d_out;               // 2560 + 65536

  float* ws = (float*)d_ws;
  float* Ball = ws;                 // 10*65536
  float* sigw = ws + 655360;        // 10*256

  bmat_kernel<<<dim3(NDEPTH * 32), dim3(256), 0, stream>>>(Wb, Ball);
  forward_kernel<<<dim3(256), dim3(256), 0, stream>>>(x, W1, b1, Wb, bb, Wl, bl, out);
  eig_kernel<<<dim3(NDEPTH), dim3(1024), 0, stream>>>(Ball, sigw);
  sig_avg_kernel<<<dim3(256), dim3(256), 0, stream>>>(sigw, out + 2560);
}